// Round 11
// baseline (343.569 us; speedup 1.0000x reference)
//
#include <hip/hip_runtime.h>

// GIN 2-layer forward, MI355X (gfx950). Round 22: channel-split gather.
//  - gather split into 2 sequential dispatches per layer: pass p reads only
//    channels [64p,64p+64) (lane owns 1 channel, 128B/row coalesced).
//    Active working set 6.4MB/pass (vs 12.8) -> higher per-XCD L2 hit
//    rate; same 3.2M total line-requests; same proven 12500-block
//    unroll-16 structure. Dispatch boundary = free temporal separation
//    (the enforcement r12's soft barriers couldn't provide).
//  - everything else identical to round 21 (274.7us).

#define N_NODES 50000
#define N_EDGES 800000
#define DIM 128
#define BN_EPS 1e-5f
#define GEMM_GRID 782           // ceil(N_NODES/64)
#define NBUCK 256
#define NPB 196                 // nodes per bucket
#define BCAP 4096               // max edges per bucket (mean 3136, 17 sigma)
#define BINA_BLOCKS 128
#define EPB 6250                // 128 * 6250 = 800000 exact
#define NSLOT 16                // stats atomic slots

using bfrag8 = __attribute__((ext_vector_type(8))) short;
using accf4  = __attribute__((ext_vector_type(4))) float;
using u16x8  = __attribute__((ext_vector_type(8))) unsigned short;

__device__ __forceinline__ float bf2f(unsigned short u) {
  union { unsigned u32; float f; } c;
  c.u32 = ((unsigned)u) << 16;
  return c.f;
}
__device__ __forceinline__ unsigned short f2bf(float f) {
  union { float f; unsigned u32; } c;
  c.f = f;
  unsigned u = c.u32;
  return (unsigned short)((u + 0x7fffu + ((u >> 16) & 1u)) >> 16);  // RNE
}

struct PPtrs { const void* xs; const void* w[4]; const void* v[10]; };

// ================= binA + prep (merged) =================
__global__ __launch_bounds__(256) void binA_kernel(
    const int* __restrict__ row, const int* __restrict__ col,
    int* __restrict__ bcnt, int* __restrict__ gcur,
    unsigned* __restrict__ ebuf, PPtrs pp,
    unsigned short* __restrict__ PW, float* __restrict__ PV,
    int* __restrict__ flag, float* __restrict__ ps2) {
  __shared__ int hist[NBUCK];
  __shared__ int lofs[NBUCK];
  __shared__ int gbase[NBUCK];
  __shared__ int cur[NBUCK];
  __shared__ unsigned seg[EPB];
  __shared__ int dstg[EPB];
  int t = threadIdx.x;
  int b = blockIdx.x;

  if (b >= BINA_BLOCKS) {
    // ---- prep path: per-block dtype detection ----
    __shared__ int oks[64];
    __shared__ int bfs;
    if (t < 64) {
      unsigned short u = ((const unsigned short*)pp.xs)[t * 2];
      int e = (u >> 7) & 0xFF;
      oks[t] = ((e >= 96 && e <= 134) || ((u & 0x7FFFu) == 0)) ? 1 : 0;
    }
    __syncthreads();
    if (t == 0) {
      int c = 0;
      for (int i = 0; i < 64; ++i) c += oks[i];
      bfs = (c >= 56) ? 1 : 0;
    }
    __syncthreads();
    int bf = bfs;
    int pb = b - BINA_BLOCKS;
    if (pb < 32) {
      int mat = pb >> 3, part = pb & 7;
      const void* src = pp.w[mat];
      unsigned short* dst = PW + (size_t)mat * 16384;
      int f = part * 256 + t;            // one fragment per thread
      int kt = f >> 9, nt = (f >> 6) & 7, lane = f & 63;
      int kbase = kt * 32 + (lane >> 4) * 8;
      int n = nt * 16 + (lane & 15);
      unsigned short tmp[8];
      for (int j = 0; j < 8; ++j) {
        int idx = (kbase + j) * DIM + n;
        if (bf) tmp[j] = ((const unsigned short*)src)[idx];
        else    tmp[j] = f2bf(((const float*)src)[idx]);
      }
      for (int j = 0; j < 8; ++j) dst[f * 8 + j] = tmp[j];
    } else {
      for (int j = t; j < 10 * DIM; j += 256) {
        int vec = j >> 7, idx = j & 127;
        float v;
        if (bf) v = bf2f(((const unsigned short*)pp.v[vec])[idx]);
        else    v = ((const float*)pp.v[vec])[idx];
        PV[j] = v;
      }
      if (t == 0) *flag = bf;
      for (int j = t; j < 3 * NSLOT * 256; j += 256) ps2[j] = 0.f;
    }
    return;
  }

  // ---- edge-binning path ----
  int e0 = b * EPB;
  hist[t] = 0;
  __syncthreads();
  for (int i = t; i < EPB; i += 256)
    atomicAdd(&hist[row[e0 + i] / NPB], 1);
  __syncthreads();
  int h = hist[t];
  lofs[t] = h;
  __syncthreads();
  for (int d = 1; d < 256; d <<= 1) {
    int v = (t >= d) ? lofs[t - d] : 0;
    __syncthreads();
    lofs[t] += v;
    __syncthreads();
  }
  int excl = lofs[t] - h;
  int gb = h ? atomicAdd(&gcur[t], h) : 0;
  if (h) atomicAdd(&bcnt[t], h);
  __syncthreads();
  lofs[t] = excl;
  cur[t] = excl;
  gbase[t] = t * BCAP + gb;      // absolute segment base for this run
  __syncthreads();
  for (int i = t; i < EPB; i += 256) {
    int r = row[e0 + i];
    int c = col[e0 + i];
    int bk = r / NPB;
    int s = atomicAdd(&cur[bk], 1);
    seg[s] = (unsigned)r | ((unsigned)c << 16);
    dstg[s] = gbase[bk] + (s - lofs[bk]);
  }
  __syncthreads();
  for (int s = t; s < EPB; s += 256)
    ebuf[dstg[s]] = seg[s];
}

// binB: redundant bcnt scan -> segbase; per-node counts recomputed from
// the bucket segment; local scan -> offs; LDS counting sort by node.
__global__ __launch_bounds__(256) void binB_kernel(
    const int* __restrict__ bcnt, const unsigned* __restrict__ ebuf,
    int* __restrict__ csr_col, int* __restrict__ offs) {
  __shared__ int sc[256];
  __shared__ int dg[256];
  __shared__ int cur[NPB];
  __shared__ int seg[BCAP];
  int b = blockIdx.x;
  int t = threadIdx.x;

  sc[t] = bcnt[t];
  __syncthreads();
  for (int d = 1; d < 256; d <<= 1) {
    int v = (t >= d) ? sc[t - d] : 0;
    __syncthreads();
    sc[t] += v;
    __syncthreads();
  }
  int segbase = (b == 0) ? 0 : sc[b - 1];

  int nb = b * NPB;
  int nend = nb + NPB;
  if (nend > N_NODES) nend = N_NODES;
  int nn = nend - nb;
  int cnt = bcnt[b];
  const unsigned* eb = ebuf + (size_t)b * BCAP;

  if (t < NPB) cur[t] = 0;
  __syncthreads();
  for (int i = t; i < cnt; i += 256) {
    int r = (int)(eb[i] & 0xFFFFu);
    atomicAdd(&cur[r - nb], 1);
  }
  __syncthreads();
  int myd = (t < nn) ? cur[t] : 0;
  dg[t] = myd;
  __syncthreads();
  for (int d = 1; d < 256; d <<= 1) {
    int v = (t >= d) ? dg[t - d] : 0;
    __syncthreads();
    dg[t] += v;
    __syncthreads();
  }
  int excl = dg[t] - myd;
  if (t < nn) {
    offs[nb + t] = segbase + excl;
    cur[t] = excl;
  }
  if (b == NBUCK - 1 && t == 0) offs[N_NODES] = N_EDGES;
  __syncthreads();
  for (int i = t; i < cnt; i += 256) {
    unsigned e = eb[i];
    int r = (int)(e & 0xFFFFu);
    int slot = atomicAdd(&cur[r - nb], 1);
    seg[slot] = (int)(e >> 16);
  }
  __syncthreads();
  for (int i = t; i < cnt; i += 256)
    csr_col[segbase + i] = seg[i];
}

// ================= channel-split gather, unroll-16 =================
// Pass p covers channels [64p, 64p+64); lane owns 1 channel (2B bf16).
// 64 lanes -> 128B coalesced half-row read; active working set 6.4MB/pass
// fits closer to per-XCD L2. Same block/unroll structure as the proven
// 56us full-row form. mode 0: plain sum; mode 1: relu(v*sc+sh).
__global__ __launch_bounds__(256, 4) void gather_row_kernel(
    const void* __restrict__ src, const int* __restrict__ offs,
    const int* __restrict__ csr_col, const float* __restrict__ stats_in,
    const float* __restrict__ gv, const float* __restrict__ bev,
    unsigned short* __restrict__ agg, const int* __restrict__ flagp,
    int mode, int pass) {
  __shared__ float ssl[256];
  int tid = threadIdx.x;
  if (mode == 1) {
    if (tid < 128) {
      float s = 0.f, q = 0.f;
#pragma unroll
      for (int k = 0; k < NSLOT; ++k) {
        s += stats_in[k * 256 + tid];
        q += stats_in[k * 256 + 128 + tid];
      }
      const float invN = 1.0f / (float)N_NODES;
      float m = s * invN;
      float v = q * invN - m * m;
      float scv = gv[tid] * rsqrtf(v + BN_EPS);
      ssl[tid] = scv;
      ssl[128 + tid] = bev[tid] - m * scv;
    }
    __syncthreads();
  }

  int node = blockIdx.x * 4 + (tid >> 6);
  if (node >= N_NODES) return;
  int lane = tid & 63;
  int ch = pass * 64 + lane;       // one channel per lane per pass
  int start = offs[node], end = offs[node + 1];
  float a0 = 0.f;
  int bf = *flagp;
  float sc0 = 0.f, sh0 = 0.f;
  if (mode == 1) {
    sc0 = ssl[ch];
    sh0 = ssl[128 + ch];
  }

  if (mode == 1 || bf) {
    const unsigned short* h = (const unsigned short*)src;
    int j = start;
    for (; j + 15 < end; j += 16) {
      int ix[16];
#pragma unroll
      for (int k = 0; k < 16; ++k) ix[k] = csr_col[j + k];
      unsigned short u[16];
#pragma unroll
      for (int k = 0; k < 16; ++k)
        u[k] = h[(size_t)ix[k] * DIM + ch];
      if (mode == 1) {
#pragma unroll
        for (int k = 0; k < 16; ++k)
          a0 += fmaxf(bf2f(u[k]) * sc0 + sh0, 0.f);
      } else {
#pragma unroll
        for (int k = 0; k < 16; ++k)
          a0 += bf2f(u[k]);
      }
    }
    if (j + 7 < end) {
      int ix[8];
#pragma unroll
      for (int k = 0; k < 8; ++k) ix[k] = csr_col[j + k];
      unsigned short u[8];
#pragma unroll
      for (int k = 0; k < 8; ++k)
        u[k] = h[(size_t)ix[k] * DIM + ch];
#pragma unroll
      for (int k = 0; k < 8; ++k) {
        if (mode == 1) a0 += fmaxf(bf2f(u[k]) * sc0 + sh0, 0.f);
        else           a0 += bf2f(u[k]);
      }
      j += 8;
    }
    if (j + 3 < end) {
      int ix[4];
#pragma unroll
      for (int k = 0; k < 4; ++k) ix[k] = csr_col[j + k];
      unsigned short u[4];
#pragma unroll
      for (int k = 0; k < 4; ++k)
        u[k] = h[(size_t)ix[k] * DIM + ch];
#pragma unroll
      for (int k = 0; k < 4; ++k) {
        if (mode == 1) a0 += fmaxf(bf2f(u[k]) * sc0 + sh0, 0.f);
        else           a0 += bf2f(u[k]);
      }
      j += 4;
    }
    for (; j < end; ++j) {
      unsigned short u = h[(size_t)csr_col[j] * DIM + ch];
      if (mode == 1) a0 += fmaxf(bf2f(u) * sc0 + sh0, 0.f);
      else           a0 += bf2f(u);
    }
  } else {
    const float* x = (const float*)src;
    int j = start;
    for (; j + 15 < end; j += 16) {
      int ix[16];
#pragma unroll
      for (int k = 0; k < 16; ++k) ix[k] = csr_col[j + k];
      float u[16];
#pragma unroll
      for (int k = 0; k < 16; ++k)
        u[k] = x[(size_t)ix[k] * DIM + ch];
#pragma unroll
      for (int k = 0; k < 16; ++k) a0 += u[k];
    }
    for (; j < end; ++j)
      a0 += x[(size_t)csr_col[j] * DIM + ch];
  }
  agg[(size_t)node * DIM + ch] = f2bf(a0);
}

// ================= MFMA GEMM (16B-wide stage, +BN in, +stats out) ========
__global__ __launch_bounds__(256) void gemm_kernel(
    const void* __restrict__ Ap, const unsigned short* __restrict__ agg,
    const unsigned short* __restrict__ PWm, const float* __restrict__ bias,
    const float* __restrict__ stats_in, const float* __restrict__ gv,
    const float* __restrict__ bev, void* __restrict__ Cp,
    float* __restrict__ stats_out, const int* __restrict__ flagp,
    int a_ext, int add_agg, int out_ext) {
  __shared__ unsigned short As[64 * 136];
  __shared__ float red_s[256];
  __shared__ float red_q[256];
  __shared__ float ssl[256];
  const int tid = threadIdx.x;
  const int row0 = blockIdx.x * 64;
  const int bf = *flagp;
  const int has_tf = (stats_in != nullptr);

  if (has_tf) {
    if (tid < 128) {
      float s = 0.f, q = 0.f;
#pragma unroll
      for (int k = 0; k < NSLOT; ++k) {
        s += stats_in[k * 256 + tid];
        q += stats_in[k * 256 + 128 + tid];
      }
      const float invN = 1.0f / (float)N_NODES;
      float m = s * invN;
      float v = q * invN - m * m;
      float scv = gv[tid] * rsqrtf(v + BN_EPS);
      ssl[tid] = scv;
      ssl[128 + tid] = bev[tid] - m * scv;
    }
    __syncthreads();
  }

  // stage: 16B per lane per iteration (4 iterations cover 64x128 bf16)
  for (int i = 0; i < 4; ++i) {
    int G = tid + i * 256;
    int lrow = G >> 4;
    int ch = (G & 15) * 8;
    int grow = row0 + lrow;
    float f[8];
    if (grow < N_NODES) {
      if (a_ext && !bf) {
        const float* xr = (const float*)Ap + (size_t)grow * DIM + ch;
        float4 v0 = *(const float4*)xr;
        float4 v1 = *(const float4*)(xr + 4);
        f[0] = v0.x; f[1] = v0.y; f[2] = v0.z; f[3] = v0.w;
        f[4] = v1.x; f[5] = v1.y; f[6] = v1.z; f[7] = v1.w;
      } else {
        u16x8 u = *(const u16x8*)((const unsigned short*)Ap +
                                  (size_t)grow * DIM + ch);
#pragma unroll
        for (int k = 0; k < 8; ++k) f[k] = bf2f(u[k]);
      }
      if (has_tf) {
#pragma unroll
        for (int k = 0; k < 8; ++k)
          f[k] = fmaxf(f[k] * ssl[ch + k] + ssl[128 + ch + k], 0.f);
      }
      if (add_agg) {
        u16x8 au = *(const u16x8*)(agg + (size_t)grow * DIM + ch);
#pragma unroll
        for (int k = 0; k < 8; ++k) f[k] += bf2f(au[k]);
      }
    } else {
#pragma unroll
      for (int k = 0; k < 8; ++k) f[k] = 0.f;
    }
    u16x8 o;
#pragma unroll
    for (int k = 0; k < 8; ++k) o[k] = f2bf(f[k]);
    *(u16x8*)&As[lrow * 136 + ch] = o;
  }
  __syncthreads();

  const int wv = tid >> 6, lane = tid & 63;
  const int quad = lane >> 4, lo = lane & 15;
  accf4 acc[8];
#pragma unroll
  for (int nt = 0; nt < 8; ++nt) {
    acc[nt][0] = 0.f; acc[nt][1] = 0.f; acc[nt][2] = 0.f; acc[nt][3] = 0.f;
  }
#pragma unroll
  for (int kt = 0; kt < 4; ++kt) {
    bfrag8 a = *(const bfrag8*)&As[(wv * 16 + lo) * 136 + kt * 32 + quad * 8];
    const unsigned short* pw = PWm + kt * 4096 + lane * 8;
#pragma unroll
    for (int nt = 0; nt < 8; ++nt) {
      bfrag8 b = *(const bfrag8*)(pw + nt * 512);
      acc[nt] = __builtin_amdgcn_mfma_f32_16x16x32_bf16(a, b, acc[nt], 0, 0, 0);
    }
  }
  __syncthreads();

  if (out_ext && !bf) {
    float* Co = (float*)Cp;
#pragma unroll
    for (int nt = 0; nt < 8; ++nt) {
      float b = bias[nt * 16 + lo];
#pragma unroll
      for (int reg = 0; reg < 4; ++reg) {
        int grow = row0 + wv * 16 + quad * 4 + reg;
        if (grow < N_NODES)
          Co[(size_t)grow * DIM + nt * 16 + lo] = acc[nt][reg] + b;
      }
    }
  } else {
#pragma unroll
    for (int nt = 0; nt < 8; ++nt) {
      float b = bias[nt * 16 + lo];
#pragma unroll
      for (int reg = 0; reg < 4; ++reg) {
        As[(wv * 16 + quad * 4 + reg) * 136 + nt * 16 + lo] =
            f2bf(acc[nt][reg] + b);
      }
    }
    __syncthreads();
    unsigned short* Co = (unsigned short*)Cp;
    for (int i = 0; i < 4; ++i) {
      int G = tid + i * 256;
      int lrow = G >> 4, ch = (G & 15) * 8;
      int grow = row0 + lrow;
      if (grow < N_NODES)
        *(u16x8*)(Co + (size_t)grow * DIM + ch) =
            *(const u16x8*)&As[lrow * 136 + ch];
    }
    if (stats_out) {
      int c = tid & 127, rh = tid >> 7;
      int rmax = N_NODES - row0;
      if (rmax > 64) rmax = 64;
      int rend = rh * 32 + 32;
      if (rend > rmax) rend = rmax;
      float s = 0.f, q = 0.f;
      for (int r = rh * 32; r < rend; ++r) {
        float v = bf2f(As[r * 136 + c]);
        s += v; q += v * v;
      }
      red_s[tid] = s; red_q[tid] = q;
      __syncthreads();
      if (tid < 128) {
        float* so = stats_out + (size_t)(blockIdx.x & (NSLOT - 1)) * 256;
        atomicAdd(so + tid, red_s[tid] + red_s[tid + 128]);
        atomicAdd(so + 128 + tid, red_q[tid] + red_q[tid + 128]);
      }
    }
  }
}

extern "C" void kernel_launch(void* const* d_in, const int* in_sizes, int n_in,
                              void* d_out, int out_size, void* d_ws, size_t ws_size,
                              hipStream_t stream) {
  const void* x  = d_in[0];
  const int* row = (const int*)d_in[1];
  const int* col = (const int*)d_in[2];

  const size_t ND = (size_t)N_NODES * DIM;
  unsigned short* agg = (unsigned short*)d_ws;        // ND bf16
  unsigned short* hA  = agg + ND;                     // ND bf16
  unsigned short* hB  = hA + ND;                      // ND bf16
  unsigned short* PW  = hB + ND;                      // 4*16384 bf16
  float* PV    = (float*)(PW + 4 * 16384);            // 10*128 fp32
  float* ps2   = PV + 10 * DIM;                       // 3*NSLOT*256 fp32
  int*   flag  = (int*)(ps2 + 3 * NSLOT * 256);       // 1 (+pad)
  int*   bcnt  = flag + 4;                            // NBUCK   (contiguous
  int*   gcur  = bcnt + NBUCK;                        // NBUCK    zero range)
  int*   offs  = gcur + NBUCK;                        // N+1
  int*   csr_col = offs + N_NODES + 1;                // E
  unsigned* ebuf = (unsigned*)(csr_col + N_EDGES);    // NBUCK*BCAP u32

  float* S0 = ps2 + 0 * NSLOT * 256;
  float* S1 = ps2 + 1 * NSLOT * 256;
  float* S2 = ps2 + 2 * NSLOT * 256;

  float* c0_b1f = PV + 0 * DIM; float* c0_gf  = PV + 1 * DIM;
  float* c0_bef = PV + 2 * DIM; float* c0_b2f = PV + 3 * DIM;
  float* bn0_gf = PV + 4 * DIM; float* bn0_bef= PV + 5 * DIM;
  float* c1_b1f = PV + 6 * DIM; float* c1_gf  = PV + 7 * DIM;
  float* c1_bef = PV + 8 * DIM; float* c1_b2f = PV + 9 * DIM;

  const int grow_grid = (N_NODES + 3) / 4;  // 12500

  PPtrs pp;
  pp.xs = x;
  pp.w[0] = d_in[3];  pp.w[1] = d_in[7];  pp.w[2] = d_in[11]; pp.w[3] = d_in[15];
  pp.v[0] = d_in[4];  pp.v[1] = d_in[5];  pp.v[2] = d_in[6];  pp.v[3] = d_in[8];
  pp.v[4] = d_in[9];  pp.v[5] = d_in[10]; pp.v[6] = d_in[12]; pp.v[7] = d_in[13];
  pp.v[8] = d_in[14]; pp.v[9] = d_in[16];

  // zero bcnt/gcur (2KB), then merged binA+prep
  hipMemsetAsync(bcnt, 0, 2 * NBUCK * sizeof(int), stream);
  binA_kernel<<<BINA_BLOCKS + 33, 256, 0, stream>>>(
      row, col, bcnt, gcur, ebuf, pp, PW, PV, flag, ps2);
  binB_kernel<<<NBUCK, 256, 0, stream>>>(bcnt, ebuf, csr_col, offs);

  // ---- conv0 ----
  gather_row_kernel<<<grow_grid, 256, 0, stream>>>(
      x, offs, csr_col, nullptr, nullptr, nullptr, agg, flag, 0, 0);
  gather_row_kernel<<<grow_grid, 256, 0, stream>>>(
      x, offs, csr_col, nullptr, nullptr, nullptr, agg, flag, 0, 1);
  gemm_kernel<<<GEMM_GRID, 256, 0, stream>>>(
      x, agg, PW + 0 * 16384, c0_b1f, nullptr, nullptr, nullptr,
      hA, S0, flag, 1, 1, 0);
  gemm_kernel<<<GEMM_GRID, 256, 0, stream>>>(
      hA, nullptr, PW + 1 * 16384, c0_b2f, S0, c0_gf, c0_bef,
      hB, S1, flag, 0, 0, 0);

  // ---- conv1 ----
  gather_row_kernel<<<grow_grid, 256, 0, stream>>>(
      hB, offs, csr_col, S1, bn0_gf, bn0_bef, agg, flag, 1, 0);
  gather_row_kernel<<<grow_grid, 256, 0, stream>>>(
      hB, offs, csr_col, S1, bn0_gf, bn0_bef, agg, flag, 1, 1);
  gemm_kernel<<<GEMM_GRID, 256, 0, stream>>>(
      hB, agg, PW + 2 * 16384, c1_b1f, S1, bn0_gf, bn0_bef,
      hA, S2, flag, 0, 1, 0);
  gemm_kernel<<<GEMM_GRID, 256, 0, stream>>>(
      hA, nullptr, PW + 3 * 16384, c1_b2f, S2, c1_gf, c1_bef,
      d_out, nullptr, flag, 0, 0, 1);
}

// Round 12
// 295.139 us; speedup vs baseline: 1.1641x; 1.1641x over previous
//
#include <hip/hip_runtime.h>

// GIN 2-layer forward, MI355X (gfx950). Round 23: forced-MLP gather.
//  Round-11 analysis: gather throughput == resident_waves x 1 outstanding
//  row-load x bytes/request / miss-latency across FOUR structures (full,
//  wide, split, persistent). At VGPR=32 the compiler serializes the
//  "unrolled" 16-load batch. Fix: inline-asm batch of 16x
//  global_load_dword (SGPR base + 32-bit voffset, 1 VGPR/addr) with
//  early-clobber dests + single trailing vmcnt(0) -> 16 outstanding/wave
//  guaranteed by register allocation. Channel-split reverted; rest
//  identical to round 21 (274.7us).

#define N_NODES 50000
#define N_EDGES 800000
#define DIM 128
#define BN_EPS 1e-5f
#define GEMM_GRID 782           // ceil(N_NODES/64)
#define NBUCK 256
#define NPB 196                 // nodes per bucket
#define BCAP 4096               // max edges per bucket (mean 3136, 17 sigma)
#define BINA_BLOCKS 128
#define EPB 6250                // 128 * 6250 = 800000 exact
#define NSLOT 16                // stats atomic slots

using bfrag8 = __attribute__((ext_vector_type(8))) short;
using accf4  = __attribute__((ext_vector_type(4))) float;
using u16x8  = __attribute__((ext_vector_type(8))) unsigned short;

__device__ __forceinline__ float bf2f(unsigned short u) {
  union { unsigned u32; float f; } c;
  c.u32 = ((unsigned)u) << 16;
  return c.f;
}
__device__ __forceinline__ unsigned short f2bf(float f) {
  union { float f; unsigned u32; } c;
  c.f = f;
  unsigned u = c.u32;
  return (unsigned short)((u + 0x7fffu + ((u >> 16) & 1u)) >> 16);  // RNE
}

struct PPtrs { const void* xs; const void* w[4]; const void* v[10]; };

// 16 independent global loads, all in flight simultaneously. SGPR base +
// 32-bit byte voffset (1 VGPR per address). Early-clobber dests force the
// allocator to keep 16 dest + 16 offset VGPRs live; the trailing vmcnt(0)
// inside the asm + data-dependence on outputs guarantees ordering.
#define GLD16(d, off, base)                                           \
  asm volatile(                                                       \
      "global_load_dword %0, %16, %[b]\n\t"                           \
      "global_load_dword %1, %17, %[b]\n\t"                           \
      "global_load_dword %2, %18, %[b]\n\t"                           \
      "global_load_dword %3, %19, %[b]\n\t"                           \
      "global_load_dword %4, %20, %[b]\n\t"                           \
      "global_load_dword %5, %21, %[b]\n\t"                           \
      "global_load_dword %6, %22, %[b]\n\t"                           \
      "global_load_dword %7, %23, %[b]\n\t"                           \
      "global_load_dword %8, %24, %[b]\n\t"                           \
      "global_load_dword %9, %25, %[b]\n\t"                           \
      "global_load_dword %10, %26, %[b]\n\t"                          \
      "global_load_dword %11, %27, %[b]\n\t"                          \
      "global_load_dword %12, %28, %[b]\n\t"                          \
      "global_load_dword %13, %29, %[b]\n\t"                          \
      "global_load_dword %14, %30, %[b]\n\t"                          \
      "global_load_dword %15, %31, %[b]\n\t"                          \
      "s_waitcnt vmcnt(0)"                                            \
      : "=&v"(d[0]), "=&v"(d[1]), "=&v"(d[2]), "=&v"(d[3]),           \
        "=&v"(d[4]), "=&v"(d[5]), "=&v"(d[6]), "=&v"(d[7]),           \
        "=&v"(d[8]), "=&v"(d[9]), "=&v"(d[10]), "=&v"(d[11]),         \
        "=&v"(d[12]), "=&v"(d[13]), "=&v"(d[14]), "=&v"(d[15])        \
      : "v"(off[0]), "v"(off[1]), "v"(off[2]), "v"(off[3]),           \
        "v"(off[4]), "v"(off[5]), "v"(off[6]), "v"(off[7]),           \
        "v"(off[8]), "v"(off[9]), "v"(off[10]), "v"(off[11]),         \
        "v"(off[12]), "v"(off[13]), "v"(off[14]), "v"(off[15]),       \
        [b] "s"(base))

// ================= binA + prep (merged) =================
__global__ __launch_bounds__(256) void binA_kernel(
    const int* __restrict__ row, const int* __restrict__ col,
    int* __restrict__ bcnt, int* __restrict__ gcur,
    unsigned* __restrict__ ebuf, PPtrs pp,
    unsigned short* __restrict__ PW, float* __restrict__ PV,
    int* __restrict__ flag, float* __restrict__ ps2) {
  __shared__ int hist[NBUCK];
  __shared__ int lofs[NBUCK];
  __shared__ int gbase[NBUCK];
  __shared__ int cur[NBUCK];
  __shared__ unsigned seg[EPB];
  __shared__ int dstg[EPB];
  int t = threadIdx.x;
  int b = blockIdx.x;

  if (b >= BINA_BLOCKS) {
    // ---- prep path: per-block dtype detection ----
    __shared__ int oks[64];
    __shared__ int bfs;
    if (t < 64) {
      unsigned short u = ((const unsigned short*)pp.xs)[t * 2];
      int e = (u >> 7) & 0xFF;
      oks[t] = ((e >= 96 && e <= 134) || ((u & 0x7FFFu) == 0)) ? 1 : 0;
    }
    __syncthreads();
    if (t == 0) {
      int c = 0;
      for (int i = 0; i < 64; ++i) c += oks[i];
      bfs = (c >= 56) ? 1 : 0;
    }
    __syncthreads();
    int bf = bfs;
    int pb = b - BINA_BLOCKS;
    if (pb < 32) {
      int mat = pb >> 3, part = pb & 7;
      const void* src = pp.w[mat];
      unsigned short* dst = PW + (size_t)mat * 16384;
      int f = part * 256 + t;            // one fragment per thread
      int kt = f >> 9, nt = (f >> 6) & 7, lane = f & 63;
      int kbase = kt * 32 + (lane >> 4) * 8;
      int n = nt * 16 + (lane & 15);
      unsigned short tmp[8];
      for (int j = 0; j < 8; ++j) {
        int idx = (kbase + j) * DIM + n;
        if (bf) tmp[j] = ((const unsigned short*)src)[idx];
        else    tmp[j] = f2bf(((const float*)src)[idx]);
      }
      for (int j = 0; j < 8; ++j) dst[f * 8 + j] = tmp[j];
    } else {
      for (int j = t; j < 10 * DIM; j += 256) {
        int vec = j >> 7, idx = j & 127;
        float v;
        if (bf) v = bf2f(((const unsigned short*)pp.v[vec])[idx]);
        else    v = ((const float*)pp.v[vec])[idx];
        PV[j] = v;
      }
      if (t == 0) *flag = bf;
      for (int j = t; j < 3 * NSLOT * 256; j += 256) ps2[j] = 0.f;
    }
    return;
  }

  // ---- edge-binning path ----
  int e0 = b * EPB;
  hist[t] = 0;
  __syncthreads();
  for (int i = t; i < EPB; i += 256)
    atomicAdd(&hist[row[e0 + i] / NPB], 1);
  __syncthreads();
  int h = hist[t];
  lofs[t] = h;
  __syncthreads();
  for (int d = 1; d < 256; d <<= 1) {
    int v = (t >= d) ? lofs[t - d] : 0;
    __syncthreads();
    lofs[t] += v;
    __syncthreads();
  }
  int excl = lofs[t] - h;
  int gb = h ? atomicAdd(&gcur[t], h) : 0;
  if (h) atomicAdd(&bcnt[t], h);
  __syncthreads();
  lofs[t] = excl;
  cur[t] = excl;
  gbase[t] = t * BCAP + gb;      // absolute segment base for this run
  __syncthreads();
  for (int i = t; i < EPB; i += 256) {
    int r = row[e0 + i];
    int c = col[e0 + i];
    int bk = r / NPB;
    int s = atomicAdd(&cur[bk], 1);
    seg[s] = (unsigned)r | ((unsigned)c << 16);
    dstg[s] = gbase[bk] + (s - lofs[bk]);
  }
  __syncthreads();
  for (int s = t; s < EPB; s += 256)
    ebuf[dstg[s]] = seg[s];
}

// binB: redundant bcnt scan -> segbase; per-node counts recomputed from
// the bucket segment; local scan -> offs; LDS counting sort by node.
__global__ __launch_bounds__(256) void binB_kernel(
    const int* __restrict__ bcnt, const unsigned* __restrict__ ebuf,
    int* __restrict__ csr_col, int* __restrict__ offs) {
  __shared__ int sc[256];
  __shared__ int dg[256];
  __shared__ int cur[NPB];
  __shared__ int seg[BCAP];
  int b = blockIdx.x;
  int t = threadIdx.x;

  sc[t] = bcnt[t];
  __syncthreads();
  for (int d = 1; d < 256; d <<= 1) {
    int v = (t >= d) ? sc[t - d] : 0;
    __syncthreads();
    sc[t] += v;
    __syncthreads();
  }
  int segbase = (b == 0) ? 0 : sc[b - 1];

  int nb = b * NPB;
  int nend = nb + NPB;
  if (nend > N_NODES) nend = N_NODES;
  int nn = nend - nb;
  int cnt = bcnt[b];
  const unsigned* eb = ebuf + (size_t)b * BCAP;

  if (t < NPB) cur[t] = 0;
  __syncthreads();
  for (int i = t; i < cnt; i += 256) {
    int r = (int)(eb[i] & 0xFFFFu);
    atomicAdd(&cur[r - nb], 1);
  }
  __syncthreads();
  int myd = (t < nn) ? cur[t] : 0;
  dg[t] = myd;
  __syncthreads();
  for (int d = 1; d < 256; d <<= 1) {
    int v = (t >= d) ? dg[t - d] : 0;
    __syncthreads();
    dg[t] += v;
    __syncthreads();
  }
  int excl = dg[t] - myd;
  if (t < nn) {
    offs[nb + t] = segbase + excl;
    cur[t] = excl;
  }
  if (b == NBUCK - 1 && t == 0) offs[N_NODES] = N_EDGES;
  __syncthreads();
  for (int i = t; i < cnt; i += 256) {
    unsigned e = eb[i];
    int r = (int)(e & 0xFFFFu);
    int slot = atomicAdd(&cur[r - nb], 1);
    seg[slot] = (int)(e >> 16);
  }
  __syncthreads();
  for (int i = t; i < cnt; i += 256)
    csr_col[segbase + i] = seg[i];
}

// ================= full-row gather, asm-forced 16-deep MLP =================
// Wave = 1 node; lane owns 2 channels (4B). Byte offset = ix*256 + lane*4.
// mode 0: plain sum; mode 1: relu(v*sc+sh) from slotted stats + g/be.
__global__ __launch_bounds__(256, 4) void gather_row_kernel(
    const void* __restrict__ src, const int* __restrict__ offs,
    const int* __restrict__ csr_col, const float* __restrict__ stats_in,
    const float* __restrict__ gv, const float* __restrict__ bev,
    unsigned short* __restrict__ agg, const int* __restrict__ flagp,
    int mode) {
  __shared__ float ssl[256];
  int tid = threadIdx.x;
  if (mode == 1) {
    if (tid < 128) {
      float s = 0.f, q = 0.f;
#pragma unroll
      for (int k = 0; k < NSLOT; ++k) {
        s += stats_in[k * 256 + tid];
        q += stats_in[k * 256 + 128 + tid];
      }
      const float invN = 1.0f / (float)N_NODES;
      float m = s * invN;
      float v = q * invN - m * m;
      float scv = gv[tid] * rsqrtf(v + BN_EPS);
      ssl[tid] = scv;
      ssl[128 + tid] = bev[tid] - m * scv;
    }
    __syncthreads();
  }

  int node = blockIdx.x * 4 + (tid >> 6);
  if (node >= N_NODES) return;
  int lane = tid & 63;
  int ch = lane * 2;
  const unsigned lbyte = (unsigned)(lane * 4);
  int start = offs[node], end = offs[node + 1];
  float a0 = 0.f, a1 = 0.f;
  int bf = *flagp;
  float sc0 = 0.f, sc1 = 0.f, sh0 = 0.f, sh1 = 0.f;
  if (mode == 1) {
    sc0 = ssl[ch]; sc1 = ssl[ch + 1];
    sh0 = ssl[128 + ch]; sh1 = ssl[128 + ch + 1];
  }

  if (mode == 1 || bf) {
    const unsigned short* h = (const unsigned short*)src;
    int j = start;
    for (; j + 15 < end; j += 16) {
      unsigned off[16];
#pragma unroll
      for (int k = 0; k < 16; ++k)
        off[k] = (unsigned)csr_col[j + k] * 256u + lbyte;
      unsigned d[16];
      GLD16(d, off, h);
      if (mode == 1) {
#pragma unroll
        for (int k = 0; k < 16; ++k) {
          a0 += fmaxf(bf2f((unsigned short)d[k]) * sc0 + sh0, 0.f);
          a1 += fmaxf(bf2f((unsigned short)(d[k] >> 16)) * sc1 + sh1, 0.f);
        }
      } else {
#pragma unroll
        for (int k = 0; k < 16; ++k) {
          a0 += bf2f((unsigned short)d[k]);
          a1 += bf2f((unsigned short)(d[k] >> 16));
        }
      }
    }
    // tails in plain C
    for (; j < end; ++j) {
      unsigned u = *(const unsigned*)(h + (size_t)csr_col[j] * DIM + ch);
      if (mode == 1) {
        a0 += fmaxf(bf2f((unsigned short)u) * sc0 + sh0, 0.f);
        a1 += fmaxf(bf2f((unsigned short)(u >> 16)) * sc1 + sh1, 0.f);
      } else {
        a0 += bf2f((unsigned short)u);
        a1 += bf2f((unsigned short)(u >> 16));
      }
    }
  } else {
    const float* x = (const float*)src;
    int j = start;
    for (; j + 7 < end; j += 8) {
      int ix[8];
#pragma unroll
      for (int k = 0; k < 8; ++k) ix[k] = csr_col[j + k];
#pragma unroll
      for (int k = 0; k < 8; ++k) {
        float2 v = *(const float2*)(x + (size_t)ix[k] * DIM + ch);
        a0 += v.x; a1 += v.y;
      }
    }
    for (; j < end; ++j) {
      float2 v = *(const float2*)(x + (size_t)csr_col[j] * DIM + ch);
      a0 += v.x; a1 += v.y;
    }
  }
  unsigned o = (unsigned)f2bf(a0) | ((unsigned)f2bf(a1) << 16);
  *(unsigned*)(agg + (size_t)node * DIM + ch) = o;
}

// ================= MFMA GEMM (16B-wide stage, +BN in, +stats out) ========
__global__ __launch_bounds__(256) void gemm_kernel(
    const void* __restrict__ Ap, const unsigned short* __restrict__ agg,
    const unsigned short* __restrict__ PWm, const float* __restrict__ bias,
    const float* __restrict__ stats_in, const float* __restrict__ gv,
    const float* __restrict__ bev, void* __restrict__ Cp,
    float* __restrict__ stats_out, const int* __restrict__ flagp,
    int a_ext, int add_agg, int out_ext) {
  __shared__ unsigned short As[64 * 136];
  __shared__ float red_s[256];
  __shared__ float red_q[256];
  __shared__ float ssl[256];
  const int tid = threadIdx.x;
  const int row0 = blockIdx.x * 64;
  const int bf = *flagp;
  const int has_tf = (stats_in != nullptr);

  if (has_tf) {
    if (tid < 128) {
      float s = 0.f, q = 0.f;
#pragma unroll
      for (int k = 0; k < NSLOT; ++k) {
        s += stats_in[k * 256 + tid];
        q += stats_in[k * 256 + 128 + tid];
      }
      const float invN = 1.0f / (float)N_NODES;
      float m = s * invN;
      float v = q * invN - m * m;
      float scv = gv[tid] * rsqrtf(v + BN_EPS);
      ssl[tid] = scv;
      ssl[128 + tid] = bev[tid] - m * scv;
    }
    __syncthreads();
  }

  // stage: 16B per lane per iteration (4 iterations cover 64x128 bf16)
  for (int i = 0; i < 4; ++i) {
    int G = tid + i * 256;
    int lrow = G >> 4;
    int ch = (G & 15) * 8;
    int grow = row0 + lrow;
    float f[8];
    if (grow < N_NODES) {
      if (a_ext && !bf) {
        const float* xr = (const float*)Ap + (size_t)grow * DIM + ch;
        float4 v0 = *(const float4*)xr;
        float4 v1 = *(const float4*)(xr + 4);
        f[0] = v0.x; f[1] = v0.y; f[2] = v0.z; f[3] = v0.w;
        f[4] = v1.x; f[5] = v1.y; f[6] = v1.z; f[7] = v1.w;
      } else {
        u16x8 u = *(const u16x8*)((const unsigned short*)Ap +
                                  (size_t)grow * DIM + ch);
#pragma unroll
        for (int k = 0; k < 8; ++k) f[k] = bf2f(u[k]);
      }
      if (has_tf) {
#pragma unroll
        for (int k = 0; k < 8; ++k)
          f[k] = fmaxf(f[k] * ssl[ch + k] + ssl[128 + ch + k], 0.f);
      }
      if (add_agg) {
        u16x8 au = *(const u16x8*)(agg + (size_t)grow * DIM + ch);
#pragma unroll
        for (int k = 0; k < 8; ++k) f[k] += bf2f(au[k]);
      }
    } else {
#pragma unroll
      for (int k = 0; k < 8; ++k) f[k] = 0.f;
    }
    u16x8 o;
#pragma unroll
    for (int k = 0; k < 8; ++k) o[k] = f2bf(f[k]);
    *(u16x8*)&As[lrow * 136 + ch] = o;
  }
  __syncthreads();

  const int wv = tid >> 6, lane = tid & 63;
  const int quad = lane >> 4, lo = lane & 15;
  accf4 acc[8];
#pragma unroll
  for (int nt = 0; nt < 8; ++nt) {
    acc[nt][0] = 0.f; acc[nt][1] = 0.f; acc[nt][2] = 0.f; acc[nt][3] = 0.f;
  }
#pragma unroll
  for (int kt = 0; kt < 4; ++kt) {
    bfrag8 a = *(const bfrag8*)&As[(wv * 16 + lo) * 136 + kt * 32 + quad * 8];
    const unsigned short* pw = PWm + kt * 4096 + lane * 8;
#pragma unroll
    for (int nt = 0; nt < 8; ++nt) {
      bfrag8 b = *(const bfrag8*)(pw + nt * 512);
      acc[nt] = __builtin_amdgcn_mfma_f32_16x16x32_bf16(a, b, acc[nt], 0, 0, 0);
    }
  }
  __syncthreads();

  if (out_ext && !bf) {
    float* Co = (float*)Cp;
#pragma unroll
    for (int nt = 0; nt < 8; ++nt) {
      float b = bias[nt * 16 + lo];
#pragma unroll
      for (int reg = 0; reg < 4; ++reg) {
        int grow = row0 + wv * 16 + quad * 4 + reg;
        if (grow < N_NODES)
          Co[(size_t)grow * DIM + nt * 16 + lo] = acc[nt][reg] + b;
      }
    }
  } else {
#pragma unroll
    for (int nt = 0; nt < 8; ++nt) {
      float b = bias[nt * 16 + lo];
#pragma unroll
      for (int reg = 0; reg < 4; ++reg) {
        As[(wv * 16 + quad * 4 + reg) * 136 + nt * 16 + lo] =
            f2bf(acc[nt][reg] + b);
      }
    }
    __syncthreads();
    unsigned short* Co = (unsigned short*)Cp;
    for (int i = 0; i < 4; ++i) {
      int G = tid + i * 256;
      int lrow = G >> 4, ch = (G & 15) * 8;
      int grow = row0 + lrow;
      if (grow < N_NODES)
        *(u16x8*)(Co + (size_t)grow * DIM + ch) =
            *(const u16x8*)&As[lrow * 136 + ch];
    }
    if (stats_out) {
      int c = tid & 127, rh = tid >> 7;
      int rmax = N_NODES - row0;
      if (rmax > 64) rmax = 64;
      int rend = rh * 32 + 32;
      if (rend > rmax) rend = rmax;
      float s = 0.f, q = 0.f;
      for (int r = rh * 32; r < rend; ++r) {
        float v = bf2f(As[r * 136 + c]);
        s += v; q += v * v;
      }
      red_s[tid] = s; red_q[tid] = q;
      __syncthreads();
      if (tid < 128) {
        float* so = stats_out + (size_t)(blockIdx.x & (NSLOT - 1)) * 256;
        atomicAdd(so + tid, red_s[tid] + red_s[tid + 128]);
        atomicAdd(so + 128 + tid, red_q[tid] + red_q[tid + 128]);
      }
    }
  }
}

extern "C" void kernel_launch(void* const* d_in, const int* in_sizes, int n_in,
                              void* d_out, int out_size, void* d_ws, size_t ws_size,
                              hipStream_t stream) {
  const void* x  = d_in[0];
  const int* row = (const int*)d_in[1];
  const int* col = (const int*)d_in[2];

  const size_t ND = (size_t)N_NODES * DIM;
  unsigned short* agg = (unsigned short*)d_ws;        // ND bf16
  unsigned short* hA  = agg + ND;                     // ND bf16
  unsigned short* hB  = hA + ND;                      // ND bf16
  unsigned short* PW  = hB + ND;                      // 4*16384 bf16
  float* PV    = (float*)(PW + 4 * 16384);            // 10*128 fp32
  float* ps2   = PV + 10 * DIM;                       // 3*NSLOT*256 fp32
  int*   flag  = (int*)(ps2 + 3 * NSLOT * 256);       // 1 (+pad)
  int*   bcnt  = flag + 4;                            // NBUCK   (contiguous
  int*   gcur  = bcnt + NBUCK;                        // NBUCK    zero range)
  int*   offs  = gcur + NBUCK;                        // N+1
  int*   csr_col = offs + N_NODES + 1;                // E
  unsigned* ebuf = (unsigned*)(csr_col + N_EDGES);    // NBUCK*BCAP u32

  float* S0 = ps2 + 0 * NSLOT * 256;
  float* S1 = ps2 + 1 * NSLOT * 256;
  float* S2 = ps2 + 2 * NSLOT * 256;

  float* c0_b1f = PV + 0 * DIM; float* c0_gf  = PV + 1 * DIM;
  float* c0_bef = PV + 2 * DIM; float* c0_b2f = PV + 3 * DIM;
  float* bn0_gf = PV + 4 * DIM; float* bn0_bef= PV + 5 * DIM;
  float* c1_b1f = PV + 6 * DIM; float* c1_gf  = PV + 7 * DIM;
  float* c1_bef = PV + 8 * DIM; float* c1_b2f = PV + 9 * DIM;

  const int grow_grid = (N_NODES + 3) / 4;  // 12500

  PPtrs pp;
  pp.xs = x;
  pp.w[0] = d_in[3];  pp.w[1] = d_in[7];  pp.w[2] = d_in[11]; pp.w[3] = d_in[15];
  pp.v[0] = d_in[4];  pp.v[1] = d_in[5];  pp.v[2] = d_in[6];  pp.v[3] = d_in[8];
  pp.v[4] = d_in[9];  pp.v[5] = d_in[10]; pp.v[6] = d_in[12]; pp.v[7] = d_in[13];
  pp.v[8] = d_in[14]; pp.v[9] = d_in[16];

  // zero bcnt/gcur (2KB), then merged binA+prep
  hipMemsetAsync(bcnt, 0, 2 * NBUCK * sizeof(int), stream);
  binA_kernel<<<BINA_BLOCKS + 33, 256, 0, stream>>>(
      row, col, bcnt, gcur, ebuf, pp, PW, PV, flag, ps2);
  binB_kernel<<<NBUCK, 256, 0, stream>>>(bcnt, ebuf, csr_col, offs);

  // ---- conv0 ----
  gather_row_kernel<<<grow_grid, 256, 0, stream>>>(
      x, offs, csr_col, nullptr, nullptr, nullptr, agg, flag, 0);
  gemm_kernel<<<GEMM_GRID, 256, 0, stream>>>(
      x, agg, PW + 0 * 16384, c0_b1f, nullptr, nullptr, nullptr,
      hA, S0, flag, 1, 1, 0);
  gemm_kernel<<<GEMM_GRID, 256, 0, stream>>>(
      hA, nullptr, PW + 1 * 16384, c0_b2f, S0, c0_gf, c0_bef,
      hB, S1, flag, 0, 0, 0);

  // ---- conv1 ----
  gather_row_kernel<<<grow_grid, 256, 0, stream>>>(
      hB, offs, csr_col, S1, bn0_gf, bn0_bef, agg, flag, 1);
  gemm_kernel<<<GEMM_GRID, 256, 0, stream>>>(
      hB, agg, PW + 2 * 16384, c1_b1f, S1, bn0_gf, bn0_bef,
      hA, S2, flag, 0, 1, 0);
  gemm_kernel<<<GEMM_GRID, 256, 0, stream>>>(
      hA, nullptr, PW + 3 * 16384, c1_b2f, S2, c1_gf, c1_bef,
      d_out, nullptr, flag, 0, 0, 1);
}

// Round 13
// 275.679 us; speedup vs baseline: 1.2463x; 1.0706x over previous
//
#include <hip/hip_runtime.h>

// GIN 2-layer forward, MI355X (gfx950). Round 24: grid-stride gather.
//  Round-12 verdict: forced 16-deep MLP (asm) left time unchanged while
//  halving FETCH -> per-CU outstanding-line budget saturates at ~21
//  resident waves x 4 lines; per-wave MLP/bytes are irrelevant. The one
//  remaining multiplier is RESIDENT WAVES (throughput ~ waves/CU).
//  Occupancy stuck at 66% from 4-wave/4-node micro-block churn + max-of-4
//  degree stragglers. Fix: 2048 blocks (8/CU exact), each wave grid-strides
//  nodes independently (no syncs) -> steady ~32 waves/CU.
//  Everything else identical to round 21 (274.7us best).

#define N_NODES 50000
#define N_EDGES 800000
#define DIM 128
#define BN_EPS 1e-5f
#define GEMM_GRID 782           // ceil(N_NODES/64)
#define NBUCK 256
#define NPB 196                 // nodes per bucket
#define BCAP 4096               // max edges per bucket (mean 3136, 17 sigma)
#define BINA_BLOCKS 128
#define EPB 6250                // 128 * 6250 = 800000 exact
#define NSLOT 16                // stats atomic slots
#define GW_BLOCKS 2048          // gather grid: exactly 8 blocks/CU
#define GW_WAVES (GW_BLOCKS * 4)

using bfrag8 = __attribute__((ext_vector_type(8))) short;
using accf4  = __attribute__((ext_vector_type(4))) float;
using u16x8  = __attribute__((ext_vector_type(8))) unsigned short;

__device__ __forceinline__ float bf2f(unsigned short u) {
  union { unsigned u32; float f; } c;
  c.u32 = ((unsigned)u) << 16;
  return c.f;
}
__device__ __forceinline__ unsigned short f2bf(float f) {
  union { float f; unsigned u32; } c;
  c.f = f;
  unsigned u = c.u32;
  return (unsigned short)((u + 0x7fffu + ((u >> 16) & 1u)) >> 16);  // RNE
}

struct PPtrs { const void* xs; const void* w[4]; const void* v[10]; };

// ================= binA + prep (merged) =================
__global__ __launch_bounds__(256) void binA_kernel(
    const int* __restrict__ row, const int* __restrict__ col,
    int* __restrict__ bcnt, int* __restrict__ gcur,
    unsigned* __restrict__ ebuf, PPtrs pp,
    unsigned short* __restrict__ PW, float* __restrict__ PV,
    int* __restrict__ flag, float* __restrict__ ps2) {
  __shared__ int hist[NBUCK];
  __shared__ int lofs[NBUCK];
  __shared__ int gbase[NBUCK];
  __shared__ int cur[NBUCK];
  __shared__ unsigned seg[EPB];
  __shared__ int dstg[EPB];
  int t = threadIdx.x;
  int b = blockIdx.x;

  if (b >= BINA_BLOCKS) {
    // ---- prep path: per-block dtype detection ----
    __shared__ int oks[64];
    __shared__ int bfs;
    if (t < 64) {
      unsigned short u = ((const unsigned short*)pp.xs)[t * 2];
      int e = (u >> 7) & 0xFF;
      oks[t] = ((e >= 96 && e <= 134) || ((u & 0x7FFFu) == 0)) ? 1 : 0;
    }
    __syncthreads();
    if (t == 0) {
      int c = 0;
      for (int i = 0; i < 64; ++i) c += oks[i];
      bfs = (c >= 56) ? 1 : 0;
    }
    __syncthreads();
    int bf = bfs;
    int pb = b - BINA_BLOCKS;
    if (pb < 32) {
      int mat = pb >> 3, part = pb & 7;
      const void* src = pp.w[mat];
      unsigned short* dst = PW + (size_t)mat * 16384;
      int f = part * 256 + t;            // one fragment per thread
      int kt = f >> 9, nt = (f >> 6) & 7, lane = f & 63;
      int kbase = kt * 32 + (lane >> 4) * 8;
      int n = nt * 16 + (lane & 15);
      unsigned short tmp[8];
      for (int j = 0; j < 8; ++j) {
        int idx = (kbase + j) * DIM + n;
        if (bf) tmp[j] = ((const unsigned short*)src)[idx];
        else    tmp[j] = f2bf(((const float*)src)[idx]);
      }
      for (int j = 0; j < 8; ++j) dst[f * 8 + j] = tmp[j];
    } else {
      for (int j = t; j < 10 * DIM; j += 256) {
        int vec = j >> 7, idx = j & 127;
        float v;
        if (bf) v = bf2f(((const unsigned short*)pp.v[vec])[idx]);
        else    v = ((const float*)pp.v[vec])[idx];
        PV[j] = v;
      }
      if (t == 0) *flag = bf;
      for (int j = t; j < 3 * NSLOT * 256; j += 256) ps2[j] = 0.f;
    }
    return;
  }

  // ---- edge-binning path ----
  int e0 = b * EPB;
  hist[t] = 0;
  __syncthreads();
  for (int i = t; i < EPB; i += 256)
    atomicAdd(&hist[row[e0 + i] / NPB], 1);
  __syncthreads();
  int h = hist[t];
  lofs[t] = h;
  __syncthreads();
  for (int d = 1; d < 256; d <<= 1) {
    int v = (t >= d) ? lofs[t - d] : 0;
    __syncthreads();
    lofs[t] += v;
    __syncthreads();
  }
  int excl = lofs[t] - h;
  int gb = h ? atomicAdd(&gcur[t], h) : 0;
  if (h) atomicAdd(&bcnt[t], h);
  __syncthreads();
  lofs[t] = excl;
  cur[t] = excl;
  gbase[t] = t * BCAP + gb;      // absolute segment base for this run
  __syncthreads();
  for (int i = t; i < EPB; i += 256) {
    int r = row[e0 + i];
    int c = col[e0 + i];
    int bk = r / NPB;
    int s = atomicAdd(&cur[bk], 1);
    seg[s] = (unsigned)r | ((unsigned)c << 16);
    dstg[s] = gbase[bk] + (s - lofs[bk]);
  }
  __syncthreads();
  for (int s = t; s < EPB; s += 256)
    ebuf[dstg[s]] = seg[s];
}

// binB: redundant bcnt scan -> segbase; per-node counts recomputed from
// the bucket segment; local scan -> offs; LDS counting sort by node.
__global__ __launch_bounds__(256) void binB_kernel(
    const int* __restrict__ bcnt, const unsigned* __restrict__ ebuf,
    int* __restrict__ csr_col, int* __restrict__ offs) {
  __shared__ int sc[256];
  __shared__ int dg[256];
  __shared__ int cur[NPB];
  __shared__ int seg[BCAP];
  int b = blockIdx.x;
  int t = threadIdx.x;

  sc[t] = bcnt[t];
  __syncthreads();
  for (int d = 1; d < 256; d <<= 1) {
    int v = (t >= d) ? sc[t - d] : 0;
    __syncthreads();
    sc[t] += v;
    __syncthreads();
  }
  int segbase = (b == 0) ? 0 : sc[b - 1];

  int nb = b * NPB;
  int nend = nb + NPB;
  if (nend > N_NODES) nend = N_NODES;
  int nn = nend - nb;
  int cnt = bcnt[b];
  const unsigned* eb = ebuf + (size_t)b * BCAP;

  if (t < NPB) cur[t] = 0;
  __syncthreads();
  for (int i = t; i < cnt; i += 256) {
    int r = (int)(eb[i] & 0xFFFFu);
    atomicAdd(&cur[r - nb], 1);
  }
  __syncthreads();
  int myd = (t < nn) ? cur[t] : 0;
  dg[t] = myd;
  __syncthreads();
  for (int d = 1; d < 256; d <<= 1) {
    int v = (t >= d) ? dg[t - d] : 0;
    __syncthreads();
    dg[t] += v;
    __syncthreads();
  }
  int excl = dg[t] - myd;
  if (t < nn) {
    offs[nb + t] = segbase + excl;
    cur[t] = excl;
  }
  if (b == NBUCK - 1 && t == 0) offs[N_NODES] = N_EDGES;
  __syncthreads();
  for (int i = t; i < cnt; i += 256) {
    unsigned e = eb[i];
    int r = (int)(e & 0xFFFFu);
    int slot = atomicAdd(&cur[r - nb], 1);
    seg[slot] = (int)(e >> 16);
  }
  __syncthreads();
  for (int i = t; i < cnt; i += 256)
    csr_col[segbase + i] = seg[i];
}

// ================= grid-stride full-row gather, unroll-16 =================
// 2048 blocks (8/CU exact); each wave independently walks nodes
// wid, wid+8192, ... with no syncs -> steady ~32 waves/CU residency.
// Per-node body identical to the proven round-15 form.
__global__ __launch_bounds__(256, 4) void gather_row_kernel(
    const void* __restrict__ src, const int* __restrict__ offs,
    const int* __restrict__ csr_col, const float* __restrict__ stats_in,
    const float* __restrict__ gv, const float* __restrict__ bev,
    unsigned short* __restrict__ agg, const int* __restrict__ flagp,
    int mode) {
  __shared__ float ssl[256];
  int tid = threadIdx.x;
  if (mode == 1) {
    if (tid < 128) {
      float s = 0.f, q = 0.f;
#pragma unroll
      for (int k = 0; k < NSLOT; ++k) {
        s += stats_in[k * 256 + tid];
        q += stats_in[k * 256 + 128 + tid];
      }
      const float invN = 1.0f / (float)N_NODES;
      float m = s * invN;
      float v = q * invN - m * m;
      float scv = gv[tid] * rsqrtf(v + BN_EPS);
      ssl[tid] = scv;
      ssl[128 + tid] = bev[tid] - m * scv;
    }
    __syncthreads();
  }

  const int wid = blockIdx.x * 4 + (tid >> 6);
  const int lane = tid & 63;
  const int ch = lane * 2;
  const int bf = *flagp;
  float sc0 = 0.f, sc1 = 0.f, sh0 = 0.f, sh1 = 0.f;
  if (mode == 1) {
    sc0 = ssl[ch]; sc1 = ssl[ch + 1];
    sh0 = ssl[128 + ch]; sh1 = ssl[128 + ch + 1];
  }

  for (int node = wid; node < N_NODES; node += GW_WAVES) {
    int start = offs[node], end = offs[node + 1];
    float a0 = 0.f, a1 = 0.f;

    if (mode == 1 || bf) {
      const unsigned short* h = (const unsigned short*)src;
      int j = start;
      for (; j + 15 < end; j += 16) {
        int ix[16];
#pragma unroll
        for (int k = 0; k < 16; ++k) ix[k] = csr_col[j + k];
        unsigned u[16];
#pragma unroll
        for (int k = 0; k < 16; ++k)
          u[k] = *(const unsigned*)(h + (size_t)ix[k] * DIM + ch);
        if (mode == 1) {
#pragma unroll
          for (int k = 0; k < 16; ++k) {
            a0 += fmaxf(bf2f((unsigned short)u[k]) * sc0 + sh0, 0.f);
            a1 += fmaxf(bf2f((unsigned short)(u[k] >> 16)) * sc1 + sh1, 0.f);
          }
        } else {
#pragma unroll
          for (int k = 0; k < 16; ++k) {
            a0 += bf2f((unsigned short)u[k]);
            a1 += bf2f((unsigned short)(u[k] >> 16));
          }
        }
      }
      if (j + 7 < end) {
        int ix[8];
#pragma unroll
        for (int k = 0; k < 8; ++k) ix[k] = csr_col[j + k];
        unsigned u[8];
#pragma unroll
        for (int k = 0; k < 8; ++k)
          u[k] = *(const unsigned*)(h + (size_t)ix[k] * DIM + ch);
#pragma unroll
        for (int k = 0; k < 8; ++k) {
          if (mode == 1) {
            a0 += fmaxf(bf2f((unsigned short)u[k]) * sc0 + sh0, 0.f);
            a1 += fmaxf(bf2f((unsigned short)(u[k] >> 16)) * sc1 + sh1, 0.f);
          } else {
            a0 += bf2f((unsigned short)u[k]);
            a1 += bf2f((unsigned short)(u[k] >> 16));
          }
        }
        j += 8;
      }
      if (j + 3 < end) {
        int ix[4];
#pragma unroll
        for (int k = 0; k < 4; ++k) ix[k] = csr_col[j + k];
        unsigned u[4];
#pragma unroll
        for (int k = 0; k < 4; ++k)
          u[k] = *(const unsigned*)(h + (size_t)ix[k] * DIM + ch);
#pragma unroll
        for (int k = 0; k < 4; ++k) {
          if (mode == 1) {
            a0 += fmaxf(bf2f((unsigned short)u[k]) * sc0 + sh0, 0.f);
            a1 += fmaxf(bf2f((unsigned short)(u[k] >> 16)) * sc1 + sh1, 0.f);
          } else {
            a0 += bf2f((unsigned short)u[k]);
            a1 += bf2f((unsigned short)(u[k] >> 16));
          }
        }
        j += 4;
      }
      for (; j < end; ++j) {
        unsigned u = *(const unsigned*)(h + (size_t)csr_col[j] * DIM + ch);
        if (mode == 1) {
          a0 += fmaxf(bf2f((unsigned short)u) * sc0 + sh0, 0.f);
          a1 += fmaxf(bf2f((unsigned short)(u >> 16)) * sc1 + sh1, 0.f);
        } else {
          a0 += bf2f((unsigned short)u);
          a1 += bf2f((unsigned short)(u >> 16));
        }
      }
    } else {
      const float* x = (const float*)src;
      int j = start;
      for (; j + 7 < end; j += 8) {
        int ix[8];
#pragma unroll
        for (int k = 0; k < 8; ++k) ix[k] = csr_col[j + k];
#pragma unroll
        for (int k = 0; k < 8; ++k) {
          float2 v = *(const float2*)(x + (size_t)ix[k] * DIM + ch);
          a0 += v.x; a1 += v.y;
        }
      }
      for (; j < end; ++j) {
        float2 v = *(const float2*)(x + (size_t)csr_col[j] * DIM + ch);
        a0 += v.x; a1 += v.y;
      }
    }
    unsigned o = (unsigned)f2bf(a0) | ((unsigned)f2bf(a1) << 16);
    *(unsigned*)(agg + (size_t)node * DIM + ch) = o;
  }
}

// ================= MFMA GEMM (16B-wide stage, +BN in, +stats out) ========
__global__ __launch_bounds__(256) void gemm_kernel(
    const void* __restrict__ Ap, const unsigned short* __restrict__ agg,
    const unsigned short* __restrict__ PWm, const float* __restrict__ bias,
    const float* __restrict__ stats_in, const float* __restrict__ gv,
    const float* __restrict__ bev, void* __restrict__ Cp,
    float* __restrict__ stats_out, const int* __restrict__ flagp,
    int a_ext, int add_agg, int out_ext) {
  __shared__ unsigned short As[64 * 136];
  __shared__ float red_s[256];
  __shared__ float red_q[256];
  __shared__ float ssl[256];
  const int tid = threadIdx.x;
  const int row0 = blockIdx.x * 64;
  const int bf = *flagp;
  const int has_tf = (stats_in != nullptr);

  if (has_tf) {
    if (tid < 128) {
      float s = 0.f, q = 0.f;
#pragma unroll
      for (int k = 0; k < NSLOT; ++k) {
        s += stats_in[k * 256 + tid];
        q += stats_in[k * 256 + 128 + tid];
      }
      const float invN = 1.0f / (float)N_NODES;
      float m = s * invN;
      float v = q * invN - m * m;
      float scv = gv[tid] * rsqrtf(v + BN_EPS);
      ssl[tid] = scv;
      ssl[128 + tid] = bev[tid] - m * scv;
    }
    __syncthreads();
  }

  // stage: 16B per lane per iteration (4 iterations cover 64x128 bf16)
  for (int i = 0; i < 4; ++i) {
    int G = tid + i * 256;
    int lrow = G >> 4;
    int ch = (G & 15) * 8;
    int grow = row0 + lrow;
    float f[8];
    if (grow < N_NODES) {
      if (a_ext && !bf) {
        const float* xr = (const float*)Ap + (size_t)grow * DIM + ch;
        float4 v0 = *(const float4*)xr;
        float4 v1 = *(const float4*)(xr + 4);
        f[0] = v0.x; f[1] = v0.y; f[2] = v0.z; f[3] = v0.w;
        f[4] = v1.x; f[5] = v1.y; f[6] = v1.z; f[7] = v1.w;
      } else {
        u16x8 u = *(const u16x8*)((const unsigned short*)Ap +
                                  (size_t)grow * DIM + ch);
#pragma unroll
        for (int k = 0; k < 8; ++k) f[k] = bf2f(u[k]);
      }
      if (has_tf) {
#pragma unroll
        for (int k = 0; k < 8; ++k)
          f[k] = fmaxf(f[k] * ssl[ch + k] + ssl[128 + ch + k], 0.f);
      }
      if (add_agg) {
        u16x8 au = *(const u16x8*)(agg + (size_t)grow * DIM + ch);
#pragma unroll
        for (int k = 0; k < 8; ++k) f[k] += bf2f(au[k]);
      }
    } else {
#pragma unroll
      for (int k = 0; k < 8; ++k) f[k] = 0.f;
    }
    u16x8 o;
#pragma unroll
    for (int k = 0; k < 8; ++k) o[k] = f2bf(f[k]);
    *(u16x8*)&As[lrow * 136 + ch] = o;
  }
  __syncthreads();

  const int wv = tid >> 6, lane = tid & 63;
  const int quad = lane >> 4, lo = lane & 15;
  accf4 acc[8];
#pragma unroll
  for (int nt = 0; nt < 8; ++nt) {
    acc[nt][0] = 0.f; acc[nt][1] = 0.f; acc[nt][2] = 0.f; acc[nt][3] = 0.f;
  }
#pragma unroll
  for (int kt = 0; kt < 4; ++kt) {
    bfrag8 a = *(const bfrag8*)&As[(wv * 16 + lo) * 136 + kt * 32 + quad * 8];
    const unsigned short* pw = PWm + kt * 4096 + lane * 8;
#pragma unroll
    for (int nt = 0; nt < 8; ++nt) {
      bfrag8 b = *(const bfrag8*)(pw + nt * 512);
      acc[nt] = __builtin_amdgcn_mfma_f32_16x16x32_bf16(a, b, acc[nt], 0, 0, 0);
    }
  }
  __syncthreads();

  if (out_ext && !bf) {
    float* Co = (float*)Cp;
#pragma unroll
    for (int nt = 0; nt < 8; ++nt) {
      float b = bias[nt * 16 + lo];
#pragma unroll
      for (int reg = 0; reg < 4; ++reg) {
        int grow = row0 + wv * 16 + quad * 4 + reg;
        if (grow < N_NODES)
          Co[(size_t)grow * DIM + nt * 16 + lo] = acc[nt][reg] + b;
      }
    }
  } else {
#pragma unroll
    for (int nt = 0; nt < 8; ++nt) {
      float b = bias[nt * 16 + lo];
#pragma unroll
      for (int reg = 0; reg < 4; ++reg) {
        As[(wv * 16 + quad * 4 + reg) * 136 + nt * 16 + lo] =
            f2bf(acc[nt][reg] + b);
      }
    }
    __syncthreads();
    unsigned short* Co = (unsigned short*)Cp;
    for (int i = 0; i < 4; ++i) {
      int G = tid + i * 256;
      int lrow = G >> 4, ch = (G & 15) * 8;
      int grow = row0 + lrow;
      if (grow < N_NODES)
        *(u16x8*)(Co + (size_t)grow * DIM + ch) =
            *(const u16x8*)&As[lrow * 136 + ch];
    }
    if (stats_out) {
      int c = tid & 127, rh = tid >> 7;
      int rmax = N_NODES - row0;
      if (rmax > 64) rmax = 64;
      int rend = rh * 32 + 32;
      if (rend > rmax) rend = rmax;
      float s = 0.f, q = 0.f;
      for (int r = rh * 32; r < rend; ++r) {
        float v = bf2f(As[r * 136 + c]);
        s += v; q += v * v;
      }
      red_s[tid] = s; red_q[tid] = q;
      __syncthreads();
      if (tid < 128) {
        float* so = stats_out + (size_t)(blockIdx.x & (NSLOT - 1)) * 256;
        atomicAdd(so + tid, red_s[tid] + red_s[tid + 128]);
        atomicAdd(so + 128 + tid, red_q[tid] + red_q[tid + 128]);
      }
    }
  }
}

extern "C" void kernel_launch(void* const* d_in, const int* in_sizes, int n_in,
                              void* d_out, int out_size, void* d_ws, size_t ws_size,
                              hipStream_t stream) {
  const void* x  = d_in[0];
  const int* row = (const int*)d_in[1];
  const int* col = (const int*)d_in[2];

  const size_t ND = (size_t)N_NODES * DIM;
  unsigned short* agg = (unsigned short*)d_ws;        // ND bf16
  unsigned short* hA  = agg + ND;                     // ND bf16
  unsigned short* hB  = hA + ND;                      // ND bf16
  unsigned short* PW  = hB + ND;                      // 4*16384 bf16
  float* PV    = (float*)(PW + 4 * 16384);            // 10*128 fp32
  float* ps2   = PV + 10 * DIM;                       // 3*NSLOT*256 fp32
  int*   flag  = (int*)(ps2 + 3 * NSLOT * 256);       // 1 (+pad)
  int*   bcnt  = flag + 4;                            // NBUCK   (contiguous
  int*   gcur  = bcnt + NBUCK;                        // NBUCK    zero range)
  int*   offs  = gcur + NBUCK;                        // N+1
  int*   csr_col = offs + N_NODES + 1;                // E
  unsigned* ebuf = (unsigned*)(csr_col + N_EDGES);    // NBUCK*BCAP u32

  float* S0 = ps2 + 0 * NSLOT * 256;
  float* S1 = ps2 + 1 * NSLOT * 256;
  float* S2 = ps2 + 2 * NSLOT * 256;

  float* c0_b1f = PV + 0 * DIM; float* c0_gf  = PV + 1 * DIM;
  float* c0_bef = PV + 2 * DIM; float* c0_b2f = PV + 3 * DIM;
  float* bn0_gf = PV + 4 * DIM; float* bn0_bef= PV + 5 * DIM;
  float* c1_b1f = PV + 6 * DIM; float* c1_gf  = PV + 7 * DIM;
  float* c1_bef = PV + 8 * DIM; float* c1_b2f = PV + 9 * DIM;

  PPtrs pp;
  pp.xs = x;
  pp.w[0] = d_in[3];  pp.w[1] = d_in[7];  pp.w[2] = d_in[11]; pp.w[3] = d_in[15];
  pp.v[0] = d_in[4];  pp.v[1] = d_in[5];  pp.v[2] = d_in[6];  pp.v[3] = d_in[8];
  pp.v[4] = d_in[9];  pp.v[5] = d_in[10]; pp.v[6] = d_in[12]; pp.v[7] = d_in[13];
  pp.v[8] = d_in[14]; pp.v[9] = d_in[16];

  // zero bcnt/gcur (2KB), then merged binA+prep
  hipMemsetAsync(bcnt, 0, 2 * NBUCK * sizeof(int), stream);
  binA_kernel<<<BINA_BLOCKS + 33, 256, 0, stream>>>(
      row, col, bcnt, gcur, ebuf, pp, PW, PV, flag, ps2);
  binB_kernel<<<NBUCK, 256, 0, stream>>>(bcnt, ebuf, csr_col, offs);

  // ---- conv0 ----
  gather_row_kernel<<<GW_BLOCKS, 256, 0, stream>>>(
      x, offs, csr_col, nullptr, nullptr, nullptr, agg, flag, 0);
  gemm_kernel<<<GEMM_GRID, 256, 0, stream>>>(
      x, agg, PW + 0 * 16384, c0_b1f, nullptr, nullptr, nullptr,
      hA, S0, flag, 1, 1, 0);
  gemm_kernel<<<GEMM_GRID, 256, 0, stream>>>(
      hA, nullptr, PW + 1 * 16384, c0_b2f, S0, c0_gf, c0_bef,
      hB, S1, flag, 0, 0, 0);

  // ---- conv1 ----
  gather_row_kernel<<<GW_BLOCKS, 256, 0, stream>>>(
      hB, offs, csr_col, S1, bn0_gf, bn0_bef, agg, flag, 1);
  gemm_kernel<<<GEMM_GRID, 256, 0, stream>>>(
      hB, agg, PW + 2 * 16384, c1_b1f, S1, bn0_gf, bn0_bef,
      hA, S2, flag, 0, 1, 0);
  gemm_kernel<<<GEMM_GRID, 256, 0, stream>>>(
      hA, nullptr, PW + 3 * 16384, c1_b2f, S2, c1_gf, c1_bef,
      d_out, nullptr, flag, 0, 0, 1);
}